// Round 4
// baseline (293.788 us; speedup 1.0000x reference)
//
#include <hip/hip_runtime.h>
#include <stdint.h>

#define NCOMP 8
#define LATD  512
#define HID   1024
#define OUTD  512
#define NS    16384

typedef unsigned short u16;
typedef __bf16 bf16x8 __attribute__((ext_vector_type(8)));
typedef float  f32x4  __attribute__((ext_vector_type(4)));

// ---- tile map: TM=128 for both gemms -> one shared map ----
#define MAPS       (NS/128 + NCOMP)        // 136 slots max
#define SLOT_CHUNK ((MAPS + 7)/8)          // 17 slots per XCD

// ---- workspace layout (bytes) ----
// offsets[9]@0, sigma[8]@64, ntiles[1]@96, map[136]@128
#define ORDER_OFF  2048
#define APACK_OFF  (ORDER_OFF + NS*4)
#define H_OFF      (APACK_OFF + (size_t)NS*LATD*2)
#define WS_NEEDED  (H_OFF + (size_t)NS*HID*2)     // ~50.5 MB

__device__ __forceinline__ u16 f2b(float f) {         // fp32 -> bf16 RNE
  unsigned int u = __builtin_bit_cast(unsigned int, f);
  u = (u + 0x7FFFu + ((u >> 16) & 1u)) >> 16;
  return (u16)u;
}

__device__ __forceinline__ void load_lds16(const void* g, void* l) {
  __builtin_amdgcn_global_load_lds((const __attribute__((address_space(1))) void*)g,
                                   (__attribute__((address_space(3))) void*)l, 16, 0, 0);
}

// ---------------- 8-WG bucketing: WG c owns comp c; no cross-WG comm ----------------
__global__ __launch_bounds__(1024)
void k_bucket8(const int* __restrict__ idx, const float* __restrict__ rho,
               int* __restrict__ offsets, float* __restrict__ sigma,
               int* __restrict__ ntiles, int* __restrict__ map,
               int* __restrict__ order) {
  __shared__ int hist_s[NCOMP];
  __shared__ int wtot[16];
  const int c = blockIdx.x;
  const int t = threadIdx.x;
  const int wave = t >> 6, lane = t & 63;

  int my[16];
  #pragma unroll
  for (int i = 0; i < 16; ++i) my[i] = idx[t + (i << 10)];

  // nibble-packed per-thread histogram (counts <=16 fit a nibble)
  unsigned long long nib = 0;
  #pragma unroll
  for (int i = 0; i < 16; ++i) nib += 1ull << (my[i] << 2);

  if (t < NCOMP) hist_s[t] = 0;
  __syncthreads();

  // full histogram: butterfly-reduce each comp across wave, one atomic per wave
  #pragma unroll
  for (int cc = 0; cc < NCOMP; ++cc) {
    int v = (int)((nib >> (cc << 2)) & 15);
    #pragma unroll
    for (int d = 1; d < 64; d <<= 1) v += __shfl_xor(v, d);
    if (lane == 0) atomicAdd(&hist_s[cc], v);
  }

  // prefix scan for comp c across 1024 threads
  int v = (int)((nib >> (c << 2)) & 15);
  int s = v;
  #pragma unroll
  for (int d = 1; d < 64; d <<= 1) {
    int u = __shfl_up(s, d);
    if (lane >= d) s += u;
  }
  if (lane == 63) wtot[wave] = s;
  __syncthreads();

  int wbase = 0;
  for (int w = 0; w < wave; ++w) wbase += wtot[w];
  int off_c = 0;
  #pragma unroll
  for (int cc = 0; cc < NCOMP; ++cc) if (cc < c) off_c += hist_s[cc];

  int pos = off_c + wbase + (s - v);
  #pragma unroll
  for (int i = 0; i < 16; ++i)
    if (my[i] == c) order[pos++] = t + (i << 10);

  if (t == 0) {
    if (c == 0) {
      int a = 0;
      for (int cc = 0; cc < NCOMP; ++cc) { offsets[cc] = a; a += hist_s[cc]; }
      offsets[NCOMP] = a;
      int tot = 0;
      for (int cc = 0; cc < NCOMP; ++cc) tot += (hist_s[cc] + 127) >> 7;
      ntiles[0] = tot;
    }
    int mb = 0;
    for (int cc = 0; cc < c; ++cc) mb += (hist_s[cc] + 127) >> 7;
    int nt = (hist_s[c] + 127) >> 7;
    for (int m = 0; m < nt; ++m) map[mb + m] = (c << 16) | m;
  }
  if (c == 0 && t < NCOMP) {
    float r = rho[t];
    sigma[t] = (r > 20.f) ? r : log1pf(expf(r));
  }
}

// ---------------- pack A: lat = eps*sigma_c + mu_c, bucket-ordered, bf16 ----------------
__global__ void k_pack(const float* __restrict__ eps, const int* __restrict__ idx,
                       const float* __restrict__ mu, const float* __restrict__ sigma,
                       const int* __restrict__ order, u16* __restrict__ Apack) {
  int g = blockIdx.x*256 + threadIdx.x;
  int i = g >> 6;
  int d = (g & 63) << 3;
  int s = order[i];
  int c = idx[s];
  float sg = sigma[c];
  const float4* ep = reinterpret_cast<const float4*>(eps + (size_t)s*LATD + d);
  const float4* mp = reinterpret_cast<const float4*>(mu  + (size_t)c*LATD + d);
  float4 e0 = ep[0], e1 = ep[1], m0 = mp[0], m1 = mp[1];
  unsigned o0 = f2b(e0.x*sg+m0.x), o1 = f2b(e0.y*sg+m0.y), o2 = f2b(e0.z*sg+m0.z), o3 = f2b(e0.w*sg+m0.w);
  unsigned o4 = f2b(e1.x*sg+m1.x), o5 = f2b(e1.y*sg+m1.y), o6 = f2b(e1.z*sg+m1.z), o7 = f2b(e1.w*sg+m1.w);
  uint4 pk;
  pk.x = o0 | (o1<<16); pk.y = o2 | (o3<<16); pk.z = o4 | (o5<<16); pk.w = o6 | (o7<<16);
  *reinterpret_cast<uint4*>(Apack + (size_t)i*LATD + d) = pk;
}

// ---------------- bf16 GEMM with fused fp32-B transpose staging ----------------
// A: [*][K] bf16 bucket-ordered (global_load_lds).  W: [C][K][NB] fp32, staged
// transposed+converted into XOR-swizzled LDS each BK=64 iter.
// Swizzle: element (n,k) at n*64 + ((k>>3 ^ ((n+(n>>3))&7))<<3) + (k&7).
// 128x128 tile, 4 waves, 4x4 16x16x32 MFMA frags. XCD slot-chunk grid.
// STAGE1: sigmoid -> bf16 H.  STAGE2: +b2 -> fp32 scatter-store via order.
template<int K, int NB, int STAGE>
__global__ __launch_bounds__(256, 4)
void k_gemm(const u16* __restrict__ A, const float* __restrict__ W,
            const int* __restrict__ offsets, const int* __restrict__ ntiles,
            const int* __restrict__ map, const int* __restrict__ order,
            const float* __restrict__ bias,
            u16* __restrict__ Hout, float* __restrict__ Yout) {
  constexpr int NCB = NB/128;
  __shared__ u16 As[128*64];
  __shared__ u16 Bs[128*64];
  __shared__ int ord[128];

  const int id    = blockIdx.x;
  const int xcd   = id & 7;
  const int sub   = id >> 3;
  const int ncolb = sub % NCB;
  const int slot  = xcd*SLOT_CHUNK + sub / NCB;
  if (slot >= ntiles[0]) return;
  const int packed = map[slot];
  const int c      = packed >> 16;
  const int bstart = offsets[c];
  const int bend   = offsets[c+1];
  const int tile0  = bstart + (packed & 0xffff)*128;
  const int ncol0  = ncolb*128;

  const int tid  = threadIdx.x;
  const int wave = tid >> 6;
  const int lane = tid & 63;
  const int srow = (wave<<5) + (lane>>3);
  const int scol = (lane&7)<<3;

  if (STAGE == 2 && tid < 128) {
    int gr = tile0 + tid;
    ord[tid] = order[gr < bend ? gr : bstart];
  }

  size_t a_off[4];
  #pragma unroll
  for (int i = 0; i < 4; ++i) {
    int ar = tile0 + srow + (i<<3);
    if (ar >= bend) ar = bend - 1;           // clamp reads (stores guarded)
    a_off[i] = (size_t)ar * K + scol;
  }

  // B staging geometry: thread handles row-pair tk (0..7), 4 cols at tn
  const int tk = tid >> 5;
  const int tn = (tid & 31) << 2;
  const float* wbase = W + (size_t)c*K*NB + ncol0 + tn;
  int swz[4];
  #pragma unroll
  for (int i = 0; i < 4; ++i) { int n = tn + i; swz[i] = (n + (n>>3)) & 7; }

  const int wr   = (wave >> 1) << 6;
  const int wc   = (wave & 1) << 6;
  const int quad = lane >> 4;
  const int l16  = lane & 15;

  int nlB[4], sB[4];
  #pragma unroll
  for (int ni = 0; ni < 4; ++ni) {
    nlB[ni] = wc + (ni<<4) + l16;
    sB[ni]  = (nlB[ni] + (nlB[ni]>>3)) & 7;
  }

  float bcol[4];
  #pragma unroll
  for (int ni = 0; ni < 4; ++ni)
    bcol[ni] = bias[(size_t)c*NB + ncol0 + wc + (ni<<4) + l16];

  f32x4 acc[4][4] = {};

  for (int k0 = 0; k0 < K; k0 += 64) {
    // A -> LDS DMA (16B/lane)
    #pragma unroll
    for (int i = 0; i < 4; ++i)
      load_lds16(A + a_off[i] + k0, &As[((wave<<5) + (i<<3))<<6]);
    // B: fp32 -> bf16 transpose into swizzled LDS, 2 half-batches
    #pragma unroll
    for (int h = 0; h < 2; ++h) {
      float4 r[4];
      #pragma unroll
      for (int p = 0; p < 2; ++p) {
        const float* src = wbase + (size_t)(k0 + ((h*2+p)<<4) + (tk<<1))*NB;
        r[2*p]   = *reinterpret_cast<const float4*>(src);
        r[2*p+1] = *reinterpret_cast<const float4*>(src + NB);
      }
      #pragma unroll
      for (int p = 0; p < 2; ++p) {
        const int kl = ((h*2+p)<<4) + (tk<<1);
        const int kc = kl >> 3;
        const float* f0 = reinterpret_cast<const float*>(&r[2*p]);
        const float* f1 = reinterpret_cast<const float*>(&r[2*p+1]);
        #pragma unroll
        for (int i = 0; i < 4; ++i) {
          // round-half-up bf16 pair pack: (hi16(f1+0x8000)<<16)|hi16(f0+0x8000)
          unsigned a0 = __builtin_bit_cast(unsigned, f0[i]) + 0x8000u;
          unsigned a1 = __builtin_bit_cast(unsigned, f1[i]) + 0x8000u;
          unsigned pk = __builtin_amdgcn_perm(a1, a0, 0x07060302u);
          *reinterpret_cast<unsigned*>(&Bs[((tn+i)<<6) + ((kc ^ swz[i])<<3) + (kl&7)]) = pk;
        }
      }
    }
    __syncthreads();
    #pragma unroll
    for (int kk = 0; kk < 64; kk += 32) {
      bf16x8 af[4], bfr[4];
      #pragma unroll
      for (int mi = 0; mi < 4; ++mi)
        af[mi] = *reinterpret_cast<const bf16x8*>(&As[((wr + (mi<<4) + l16)<<6) + kk + (quad<<3)]);
      #pragma unroll
      for (int ni = 0; ni < 4; ++ni) {
        const int kc = (kk>>3) + quad;
        bfr[ni] = *reinterpret_cast<const bf16x8*>(&Bs[(nlB[ni]<<6) + ((kc ^ sB[ni])<<3)]);
      }
      #pragma unroll
      for (int mi = 0; mi < 4; ++mi)
        #pragma unroll
        for (int ni = 0; ni < 4; ++ni)
          acc[mi][ni] = __builtin_amdgcn_mfma_f32_16x16x32_bf16(af[mi], bfr[ni], acc[mi][ni], 0, 0, 0);
    }
    __syncthreads();
  }

  // epilogue: C/D layout col=lane&15, row=quad*4+reg
  #pragma unroll
  for (int mi = 0; mi < 4; ++mi) {
    #pragma unroll
    for (int r = 0; r < 4; ++r) {
      const int row_l = wr + (mi<<4) + (quad<<2) + r;
      const int grow  = tile0 + row_l;
      if (grow < bend) {
        #pragma unroll
        for (int ni = 0; ni < 4; ++ni) {
          const int col = ncol0 + wc + (ni<<4) + l16;
          float v = acc[mi][ni][r] + bcol[ni];
          if (STAGE == 1) {
            v = 1.0f / (1.0f + __expf(-v));
            Hout[(size_t)grow*NB + col] = f2b(v);
          } else {
            Yout[(size_t)ord[row_l]*NB + col] = v;
          }
        }
      }
    }
  }
}

// ---------------- fallback (ws too small): naive per-sample MLP ----------------
__global__ void k_naive(const float* __restrict__ eps, const int* __restrict__ idx,
                        const float* __restrict__ mu, const float* __restrict__ rho,
                        const float* __restrict__ W1, const float* __restrict__ b1,
                        const float* __restrict__ W2, const float* __restrict__ b2,
                        float* __restrict__ out) {
  __shared__ float lat[LATD];
  __shared__ float h[HID];
  int n = blockIdx.x, t = threadIdx.x;
  int c = idx[n];
  float r = rho[c];
  float sg = (r > 20.f) ? r : log1pf(expf(r));
  for (int d = t; d < LATD; d += 256) lat[d] = eps[(size_t)n*LATD+d]*sg + mu[(size_t)c*LATD+d];
  __syncthreads();
  for (int j = t; j < HID; j += 256) {
    float a = b1[(size_t)c*HID+j];
    const float* w = W1 + (size_t)c*LATD*HID + j;
    for (int d = 0; d < LATD; ++d) a += lat[d]*w[(size_t)d*HID];
    h[j] = 1.f/(1.f+expf(-a));
  }
  __syncthreads();
  for (int o = t; o < OUTD; o += 256) {
    float a = b2[(size_t)c*OUTD+o];
    const float* w = W2 + (size_t)c*HID*OUTD + o;
    for (int j = 0; j < HID; ++j) a += h[j]*w[(size_t)j*OUTD];
    out[(size_t)n*OUTD+o] = a;
  }
}

extern "C" void kernel_launch(void* const* d_in, const int* in_sizes, int n_in,
                              void* d_out, int out_size, void* d_ws, size_t ws_size,
                              hipStream_t stream) {
  const float* eps = (const float*)d_in[0];
  const int*   idx = (const int*)d_in[1];
  const float* mu  = (const float*)d_in[2];
  const float* rho = (const float*)d_in[3];
  const float* W1  = (const float*)d_in[4];
  const float* b1  = (const float*)d_in[5];
  const float* W2  = (const float*)d_in[6];
  const float* b2  = (const float*)d_in[7];
  float* out = (float*)d_out;

  if (ws_size < WS_NEEDED) {     // insurance only
    k_naive<<<NS, 256, 0, stream>>>(eps, idx, mu, rho, W1, b1, W2, b2, out);
    return;
  }

  char* ws = (char*)d_ws;
  int*   offsets = (int*)(ws + 0);
  float* sigma   = (float*)(ws + 64);
  int*   ntiles  = (int*)(ws + 96);
  int*   map     = (int*)(ws + 128);
  int*   order   = (int*)(ws + ORDER_OFF);
  u16*   Apack   = (u16*)(ws + APACK_OFF);
  u16*   Hws     = (u16*)(ws + H_OFF);

  k_bucket8<<<NCOMP, 1024, 0, stream>>>(idx, rho, offsets, sigma, ntiles, map, order);
  k_pack   <<<NS*64/256, 256, 0, stream>>>(eps, idx, mu, sigma, order, Apack);
  // GEMM1: [Nc x 512] @ [512 x 1024] -> sigmoid -> H (bf16); B = W1 fp32 in-kernel
  k_gemm<LATD, HID, 1><<<8*SLOT_CHUNK*(HID/128), 256, 0, stream>>>(
      Apack, W1, offsets, ntiles, map, order, b1, Hws, nullptr);
  // GEMM2: [Nc x 1024] @ [1024 x 512] -> +b2 -> fp32 scatter out; B = W2 fp32 in-kernel
  k_gemm<HID, OUTD, 2><<<8*SLOT_CHUNK*(OUTD/128), 256, 0, stream>>>(
      Hws, W2, offsets, ntiles, map, order, b2, nullptr, out);
}

// Round 5
// 223.362 us; speedup vs baseline: 1.3153x; 1.3153x over previous
//
#include <hip/hip_runtime.h>
#include <stdint.h>

#define NCOMP 8
#define LATD  512
#define HID   1024
#define OUTD  512
#define NS    16384

typedef unsigned short u16;
typedef __bf16 bf16x8 __attribute__((ext_vector_type(8)));
typedef float  f32x4  __attribute__((ext_vector_type(4)));

// ---- tile map: TM=128 for both gemms -> one shared map ----
#define MAPS       (NS/128 + NCOMP)        // 136 slots max
#define SLOT_CHUNK ((MAPS + 7)/8)          // 17 slots per XCD

// ---- workspace layout (bytes) ----
// offsets[9]@0, sigma[8]@64, ntiles[1]@96, map[136]@128
#define ORDER_OFF  2048
#define APACK_OFF  (ORDER_OFF + NS*4)
#define W1T_OFF    (APACK_OFF + (size_t)NS*LATD*2)
#define W2T_OFF    (W1T_OFF + (size_t)NCOMP*LATD*HID*2)
#define H_OFF      (W2T_OFF + (size_t)NCOMP*HID*OUTD*2)
#define WS_NEEDED  (H_OFF + (size_t)NS*HID*2)

__device__ __forceinline__ u16 f2b(float f) {         // fp32 -> bf16 RNE
  unsigned int u = __builtin_bit_cast(unsigned int, f);
  u = (u + 0x7FFFu + ((u >> 16) & 1u)) >> 16;
  return (u16)u;
}

__device__ __forceinline__ void load_lds16(const void* g, void* l) {
  __builtin_amdgcn_global_load_lds((const __attribute__((address_space(1))) void*)g,
                                   (__attribute__((address_space(3))) void*)l, 16, 0, 0);
}

// ---------------- 8-WG bucketing: WG c owns comp c; no cross-WG comm ----------------
__global__ __launch_bounds__(1024)
void k_bucket8(const int* __restrict__ idx, const float* __restrict__ rho,
               int* __restrict__ offsets, float* __restrict__ sigma,
               int* __restrict__ ntiles, int* __restrict__ map,
               int* __restrict__ order) {
  __shared__ int hist_s[NCOMP];
  __shared__ int wtot[16];
  const int c = blockIdx.x;
  const int t = threadIdx.x;
  const int wave = t >> 6, lane = t & 63;

  int my[16];
  #pragma unroll
  for (int i = 0; i < 16; ++i) my[i] = idx[t + (i << 10)];

  // nibble-packed per-thread histogram (counts <=16 fit a nibble)
  unsigned long long nib = 0;
  #pragma unroll
  for (int i = 0; i < 16; ++i) nib += 1ull << (my[i] << 2);

  if (t < NCOMP) hist_s[t] = 0;
  __syncthreads();

  // full histogram: butterfly-reduce each comp across wave, one atomic per wave
  #pragma unroll
  for (int cc = 0; cc < NCOMP; ++cc) {
    int v = (int)((nib >> (cc << 2)) & 15);
    #pragma unroll
    for (int d = 1; d < 64; d <<= 1) v += __shfl_xor(v, d);
    if (lane == 0) atomicAdd(&hist_s[cc], v);
  }

  // prefix scan for comp c across 1024 threads
  int v = (int)((nib >> (c << 2)) & 15);
  int s = v;
  #pragma unroll
  for (int d = 1; d < 64; d <<= 1) {
    int u = __shfl_up(s, d);
    if (lane >= d) s += u;
  }
  if (lane == 63) wtot[wave] = s;
  __syncthreads();

  int wbase = 0;
  for (int w = 0; w < wave; ++w) wbase += wtot[w];
  int off_c = 0;
  #pragma unroll
  for (int cc = 0; cc < NCOMP; ++cc) if (cc < c) off_c += hist_s[cc];

  int pos = off_c + wbase + (s - v);
  #pragma unroll
  for (int i = 0; i < 16; ++i)
    if (my[i] == c) order[pos++] = t + (i << 10);

  if (t == 0) {
    if (c == 0) {
      int a = 0;
      for (int cc = 0; cc < NCOMP; ++cc) { offsets[cc] = a; a += hist_s[cc]; }
      offsets[NCOMP] = a;
      int tot = 0;
      for (int cc = 0; cc < NCOMP; ++cc) tot += (hist_s[cc] + 127) >> 7;
      ntiles[0] = tot;
    }
    int mb = 0;
    for (int cc = 0; cc < c; ++cc) mb += (hist_s[cc] + 127) >> 7;
    int nt = (hist_s[c] + 127) >> 7;
    for (int m = 0; m < nt; ++m) map[mb + m] = (c << 16) | m;
  }
  if (c == 0 && t < NCOMP) {
    float r = rho[t];
    sigma[t] = (r > 20.f) ? r : log1pf(expf(r));
  }
}

// ---------------- fused prep: pack A (blocks 0..4095) + W transpose (4096..6143) ----------------
__global__ void k_prep(const float* __restrict__ eps, const int* __restrict__ idx,
                       const float* __restrict__ mu, const float* __restrict__ sigma,
                       const int* __restrict__ order, u16* __restrict__ Apack,
                       const float* __restrict__ W1, const float* __restrict__ W2,
                       u16* __restrict__ W1T, u16* __restrict__ W2T) {
  __shared__ float tile[64][65];
  int b = blockIdx.x;
  if (b < 4096) {
    // pack: lat = eps*sigma_c + mu_c, bucket-ordered, bf16
    int g = b*256 + threadIdx.x;
    int i = g >> 6;
    int d = (g & 63) << 3;
    int s = order[i];
    int c = idx[s];
    float sg = sigma[c];
    const float4* ep = reinterpret_cast<const float4*>(eps + (size_t)s*LATD + d);
    const float4* mp = reinterpret_cast<const float4*>(mu  + (size_t)c*LATD + d);
    float4 e0 = ep[0], e1 = ep[1], m0 = mp[0], m1 = mp[1];
    unsigned o0 = f2b(e0.x*sg+m0.x), o1 = f2b(e0.y*sg+m0.y), o2 = f2b(e0.z*sg+m0.z), o3 = f2b(e0.w*sg+m0.w);
    unsigned o4 = f2b(e1.x*sg+m1.x), o5 = f2b(e1.y*sg+m1.y), o6 = f2b(e1.z*sg+m1.z), o7 = f2b(e1.w*sg+m1.w);
    uint4 pk;
    pk.x = o0 | (o1<<16); pk.y = o2 | (o3<<16); pk.z = o4 | (o5<<16); pk.w = o6 | (o7<<16);
    *reinterpret_cast<uint4*>(Apack + (size_t)i*LATD + d) = pk;
  } else {
    // transpose+convert: W [C][R][CC] fp32 -> WT [C][CC][R] bf16
    int bb = b - 4096;
    const float* src; u16* dst; int R, CC, r0, c0;
    if (bb < 1024) {       // W1: [C][512][1024], 128 blocks/comp (16 c x 8 r)
      int comp = bb >> 7, loc = bb & 127;
      R = LATD; CC = HID;
      c0 = (loc & 15) << 6; r0 = (loc >> 4) << 6;
      src = W1 + (size_t)comp*R*CC; dst = W1T + (size_t)comp*R*CC;
    } else {               // W2: [C][1024][512], 128 blocks/comp (8 c x 16 r)
      int b2 = bb - 1024;
      int comp = b2 >> 7, loc = b2 & 127;
      R = HID; CC = OUTD;
      c0 = (loc & 7) << 6; r0 = (loc >> 3) << 6;
      src = W2 + (size_t)comp*R*CC; dst = W2T + (size_t)comp*R*CC;
    }
    int tx = threadIdx.x & 63, ty = threadIdx.x >> 6;
    for (int rr = ty; rr < 64; rr += 4)
      tile[rr][tx] = src[(size_t)(r0+rr)*CC + c0 + tx];
    __syncthreads();
    for (int rr = ty; rr < 64; rr += 4)
      dst[(size_t)(c0+rr)*R + r0 + tx] = f2b(tile[tx][rr]);
  }
}

// ---------------- tile-mapped bf16 GEMM, 128x128, double-buffered LDS ----------------
// A: [*][K] bf16 bucket-ordered rows.  BT: [C][NB][K] bf16 (B^T).
// 4 waves (2m x 2n), 4x4 16x16x32 MFMA frags/wave, BK=64, global_load_lds w=16.
// ONE barrier per K-iter: barrier (drains buf p DMA) -> issue DMA it+1 into
// buf 1-p -> compute on p. DMA flight overlaps compute.
// Grid 1-D = 8 * SLOT_CHUNK * (NB/128); xcd=id&7 owns a contiguous slot chunk.
// STAGE1: sigmoid -> bf16 H.  STAGE2: +b2 -> fp32 scatter-store via order.
template<int K, int NB, int STAGE>
__global__ __launch_bounds__(256, 2)
void k_gemm(const u16* __restrict__ A, const u16* __restrict__ BT,
            const int* __restrict__ offsets, const int* __restrict__ ntiles,
            const int* __restrict__ map, const int* __restrict__ order,
            const float* __restrict__ bias,
            u16* __restrict__ Hout, float* __restrict__ Yout) {
  constexpr int NCB = NB/128;
  constexpr int NIT = K/64;
  __shared__ u16 As[2][128*64];
  __shared__ u16 Bs[2][128*64];
  __shared__ int ord[128];

  const int id    = blockIdx.x;
  const int xcd   = id & 7;
  const int sub   = id >> 3;
  const int ncolb = sub % NCB;
  const int slot  = xcd*SLOT_CHUNK + sub / NCB;
  if (slot >= ntiles[0]) return;
  const int packed = map[slot];
  const int c      = packed >> 16;
  const int bstart = offsets[c];
  const int bend   = offsets[c+1];
  const int tile0  = bstart + (packed & 0xffff)*128;
  const int ncol0  = ncolb*128;

  const int tid  = threadIdx.x;
  const int wave = tid >> 6;
  const int lane = tid & 63;
  const int srow = (wave<<5) + (lane>>3);
  const int scol = (lane&7)<<3;

  if (STAGE == 2 && tid < 128) {
    int gr = tile0 + tid;
    ord[tid] = order[gr < bend ? gr : bstart];
  }

  size_t a_off[4], b_off[4];
  const size_t bbase = (size_t)c * NB * K;
  #pragma unroll
  for (int i = 0; i < 4; ++i) {
    int ar = tile0 + srow + (i<<3);
    if (ar >= bend) ar = bend - 1;           // clamp reads (stores guarded)
    a_off[i] = (size_t)ar * K + scol;
    b_off[i] = bbase + (size_t)(ncol0 + srow + (i<<3)) * K + scol;
  }

  const int wr   = (wave >> 1) << 6;
  const int wc   = (wave & 1) << 6;
  const int quad = lane >> 4;
  const int l16  = lane & 15;

  float bcol[4];
  #pragma unroll
  for (int ni = 0; ni < 4; ++ni)
    bcol[ni] = bias[(size_t)c*NB + ncol0 + wc + (ni<<4) + l16];

  f32x4 acc[4][4] = {};

  auto stage = [&](int k0, int p) {
    #pragma unroll
    for (int i = 0; i < 4; ++i)
      load_lds16(A + a_off[i] + k0, &As[p][((wave<<5) + (i<<3))<<6]);
    #pragma unroll
    for (int i = 0; i < 4; ++i)
      load_lds16(BT + b_off[i] + k0, &Bs[p][((wave<<5) + (i<<3))<<6]);
  };

  stage(0, 0);
  for (int it = 0; it < NIT; ++it) {
    const int p = it & 1;
    __syncthreads();                       // drains buf p's DMA; buf 1-p now free
    if (it + 1 < NIT) stage((it+1)*64, p^1);
    #pragma unroll
    for (int kk = 0; kk < 64; kk += 32) {
      bf16x8 af[4], bfr[4];
      #pragma unroll
      for (int mi = 0; mi < 4; ++mi)
        af[mi] = *reinterpret_cast<const bf16x8*>(&As[p][((wr + (mi<<4) + l16)<<6) + kk + (quad<<3)]);
      #pragma unroll
      for (int ni = 0; ni < 4; ++ni)
        bfr[ni] = *reinterpret_cast<const bf16x8*>(&Bs[p][((wc + (ni<<4) + l16)<<6) + kk + (quad<<3)]);
      #pragma unroll
      for (int mi = 0; mi < 4; ++mi)
        #pragma unroll
        for (int ni = 0; ni < 4; ++ni)
          acc[mi][ni] = __builtin_amdgcn_mfma_f32_16x16x32_bf16(af[mi], bfr[ni], acc[mi][ni], 0, 0, 0);
    }
  }

  // epilogue: C/D layout col=lane&15, row=quad*4+reg
  #pragma unroll
  for (int mi = 0; mi < 4; ++mi) {
    #pragma unroll
    for (int r = 0; r < 4; ++r) {
      const int row_l = wr + (mi<<4) + (quad<<2) + r;
      const int grow  = tile0 + row_l;
      if (grow < bend) {
        #pragma unroll
        for (int ni = 0; ni < 4; ++ni) {
          const int col = ncol0 + wc + (ni<<4) + l16;
          float v = acc[mi][ni][r] + bcol[ni];
          if (STAGE == 1) {
            v = 1.0f / (1.0f + __expf(-v));
            Hout[(size_t)grow*NB + col] = f2b(v);
          } else {
            Yout[(size_t)ord[row_l]*NB + col] = v;
          }
        }
      }
    }
  }
}

// ---------------- fallback (ws too small): naive per-sample MLP ----------------
__global__ void k_naive(const float* __restrict__ eps, const int* __restrict__ idx,
                        const float* __restrict__ mu, const float* __restrict__ rho,
                        const float* __restrict__ W1, const float* __restrict__ b1,
                        const float* __restrict__ W2, const float* __restrict__ b2,
                        float* __restrict__ out) {
  __shared__ float lat[LATD];
  __shared__ float h[HID];
  int n = blockIdx.x, t = threadIdx.x;
  int c = idx[n];
  float r = rho[c];
  float sg = (r > 20.f) ? r : log1pf(expf(r));
  for (int d = t; d < LATD; d += 256) lat[d] = eps[(size_t)n*LATD+d]*sg + mu[(size_t)c*LATD+d];
  __syncthreads();
  for (int j = t; j < HID; j += 256) {
    float a = b1[(size_t)c*HID+j];
    const float* w = W1 + (size_t)c*LATD*HID + j;
    for (int d = 0; d < LATD; ++d) a += lat[d]*w[(size_t)d*HID];
    h[j] = 1.f/(1.f+expf(-a));
  }
  __syncthreads();
  for (int o = t; o < OUTD; o += 256) {
    float a = b2[(size_t)c*OUTD+o];
    const float* w = W2 + (size_t)c*HID*OUTD + o;
    for (int j = 0; j < HID; ++j) a += h[j]*w[(size_t)j*OUTD];
    out[(size_t)n*OUTD+o] = a;
  }
}

extern "C" void kernel_launch(void* const* d_in, const int* in_sizes, int n_in,
                              void* d_out, int out_size, void* d_ws, size_t ws_size,
                              hipStream_t stream) {
  const float* eps = (const float*)d_in[0];
  const int*   idx = (const int*)d_in[1];
  const float* mu  = (const float*)d_in[2];
  const float* rho = (const float*)d_in[3];
  const float* W1  = (const float*)d_in[4];
  const float* b1  = (const float*)d_in[5];
  const float* W2  = (const float*)d_in[6];
  const float* b2  = (const float*)d_in[7];
  float* out = (float*)d_out;

  if (ws_size < WS_NEEDED) {     // insurance only
    k_naive<<<NS, 256, 0, stream>>>(eps, idx, mu, rho, W1, b1, W2, b2, out);
    return;
  }

  char* ws = (char*)d_ws;
  int*   offsets = (int*)(ws + 0);
  float* sigma   = (float*)(ws + 64);
  int*   ntiles  = (int*)(ws + 96);
  int*   map     = (int*)(ws + 128);
  int*   order   = (int*)(ws + ORDER_OFF);
  u16*   Apack   = (u16*)(ws + APACK_OFF);
  u16*   W1T     = (u16*)(ws + W1T_OFF);
  u16*   W2T     = (u16*)(ws + W2T_OFF);
  u16*   Hws     = (u16*)(ws + H_OFF);

  k_bucket8<<<NCOMP, 1024, 0, stream>>>(idx, rho, offsets, sigma, ntiles, map, order);
  k_prep  <<<4096 + 2048, 256, 0, stream>>>(eps, idx, mu, sigma, order, Apack, W1, W2, W1T, W2T);
  // GEMM1: [Nc x 512] @ [512 x 1024] -> sigmoid -> H (bf16)
  k_gemm<LATD, HID, 1><<<8*SLOT_CHUNK*(HID/128), 256, 0, stream>>>(
      Apack, W1T, offsets, ntiles, map, order, b1, Hws, nullptr);
  // GEMM2: [Nc x 1024] @ [1024 x 512] -> +b2 -> scatter fp32 out
  k_gemm<HID, OUTD, 2><<<8*SLOT_CHUNK*(OUTD/128), 256, 0, stream>>>(
      Hws, W2T, offsets, ntiles, map, order, b2, nullptr, out);
}

// Round 6
// 193.121 us; speedup vs baseline: 1.5213x; 1.1566x over previous
//
#include <hip/hip_runtime.h>
#include <stdint.h>

#define NCOMP 8
#define LATD  512
#define HID   1024
#define OUTD  512
#define NS    16384

typedef unsigned short u16;
typedef __bf16 bf16x8 __attribute__((ext_vector_type(8)));
typedef float  f32x4  __attribute__((ext_vector_type(4)));

// ---- tile map: TM=128 for both gemms -> one shared map ----
#define MAPS       (NS/128 + NCOMP)        // 136 slots max
#define SLOT_CHUNK ((MAPS + 7)/8)          // 17 slots per XCD

// ---- workspace layout (bytes) ----
// offsets[9]@0, ntiles[1]@96, map[136]@128
#define ORDER_OFF  2048
#define APACK_OFF  (ORDER_OFF + NS*4)
#define W1T_OFF    (APACK_OFF + (size_t)NS*LATD*2)
#define W2T_OFF    (W1T_OFF + (size_t)NCOMP*LATD*HID*2)
#define H_OFF      (W2T_OFF + (size_t)NCOMP*HID*OUTD*2)
#define WS_NEEDED  (H_OFF + (size_t)NS*HID*2)

__device__ __forceinline__ u16 f2b(float f) {         // fp32 -> bf16 RNE
  unsigned int u = __builtin_bit_cast(unsigned int, f);
  u = (u + 0x7FFFu + ((u >> 16) & 1u)) >> 16;
  return (u16)u;
}

__device__ __forceinline__ void load_lds16(const void* g, void* l) {
  __builtin_amdgcn_global_load_lds((const __attribute__((address_space(1))) void*)g,
                                   (__attribute__((address_space(3))) void*)l, 16, 0, 0);
}

// ---------------- ONE prep dispatch ----------------
// blocks 0..7          : bucketing (block c owns comp c; no cross-block comm)
// blocks 8..1031       : pack A in ORIGINAL sample order (no `order` dependency)
// blocks 1032..3079    : W1/W2 transpose+convert fp32 -> bf16
__global__ __launch_bounds__(1024)
void k_prep_all(const int* __restrict__ idx, const float* __restrict__ rho,
                const float* __restrict__ eps, const float* __restrict__ mu,
                const float* __restrict__ W1, const float* __restrict__ W2,
                int* __restrict__ offsets, int* __restrict__ ntiles,
                int* __restrict__ map, int* __restrict__ order,
                u16* __restrict__ Apack, u16* __restrict__ W1T, u16* __restrict__ W2T) {
  __shared__ float tile[64][65];      // wtrans path
  __shared__ int hist_s[NCOMP];       // bucket path
  __shared__ int wtot[16];
  const int b = blockIdx.x;
  const int t = threadIdx.x;

  if (b < NCOMP) {
    // ---- bucketing: block c owns comp c ----
    const int c = b;
    const int wave = t >> 6, lane = t & 63;

    int my[16];
    #pragma unroll
    for (int i = 0; i < 16; ++i) my[i] = idx[t + (i << 10)];

    unsigned long long nib = 0;        // nibble-packed per-thread hist (<=16/comp)
    #pragma unroll
    for (int i = 0; i < 16; ++i) nib += 1ull << (my[i] << 2);

    if (t < NCOMP) hist_s[t] = 0;
    __syncthreads();

    #pragma unroll
    for (int cc = 0; cc < NCOMP; ++cc) {
      int v = (int)((nib >> (cc << 2)) & 15);
      #pragma unroll
      for (int d = 1; d < 64; d <<= 1) v += __shfl_xor(v, d);
      if (lane == 0) atomicAdd(&hist_s[cc], v);
    }

    int v = (int)((nib >> (c << 2)) & 15);
    int s = v;
    #pragma unroll
    for (int d = 1; d < 64; d <<= 1) {
      int u = __shfl_up(s, d);
      if (lane >= d) s += u;
    }
    if (lane == 63) wtot[wave] = s;
    __syncthreads();

    int wbase = 0;
    for (int w = 0; w < wave; ++w) wbase += wtot[w];
    int off_c = 0;
    #pragma unroll
    for (int cc = 0; cc < NCOMP; ++cc) if (cc < c) off_c += hist_s[cc];

    int pos = off_c + wbase + (s - v);
    #pragma unroll
    for (int i = 0; i < 16; ++i)
      if (my[i] == c) order[pos++] = t + (i << 10);

    if (t == 0) {
      if (c == 0) {
        int a = 0;
        for (int cc = 0; cc < NCOMP; ++cc) { offsets[cc] = a; a += hist_s[cc]; }
        offsets[NCOMP] = a;
        int tot = 0;
        for (int cc = 0; cc < NCOMP; ++cc) tot += (hist_s[cc] + 127) >> 7;
        ntiles[0] = tot;
      }
      int mb = 0;
      for (int cc = 0; cc < c; ++cc) mb += (hist_s[cc] + 127) >> 7;
      int nt = (hist_s[c] + 127) >> 7;
      for (int m = 0; m < nt; ++m) map[mb + m] = (c << 16) | m;
    }
  } else if (b < NCOMP + 1024) {
    // ---- pack: lat[i] = eps[i]*softplus(rho[idx[i]]) + mu[idx[i]], original order ----
    int g = (b - NCOMP) * 1024 + t;
    int i = g >> 6;                   // sample (64 threads/sample)
    int d = (g & 63) << 3;
    int c = idx[i];                   // broadcast within the 64-thread group
    float r = rho[c];
    float sg = (r > 20.f) ? r : log1pf(expf(r));
    const float4* ep = reinterpret_cast<const float4*>(eps + (size_t)i*LATD + d);
    const float4* mp = reinterpret_cast<const float4*>(mu  + (size_t)c*LATD + d);
    float4 e0 = ep[0], e1 = ep[1], m0 = mp[0], m1 = mp[1];
    unsigned o0 = f2b(e0.x*sg+m0.x), o1 = f2b(e0.y*sg+m0.y), o2 = f2b(e0.z*sg+m0.z), o3 = f2b(e0.w*sg+m0.w);
    unsigned o4 = f2b(e1.x*sg+m1.x), o5 = f2b(e1.y*sg+m1.y), o6 = f2b(e1.z*sg+m1.z), o7 = f2b(e1.w*sg+m1.w);
    uint4 pk;
    pk.x = o0 | (o1<<16); pk.y = o2 | (o3<<16); pk.z = o4 | (o5<<16); pk.w = o6 | (o7<<16);
    *reinterpret_cast<uint4*>(Apack + (size_t)i*LATD + d) = pk;
  } else {
    // ---- transpose+convert: W [C][R][CC] fp32 -> WT [C][CC][R] bf16 ----
    int bb = b - (NCOMP + 1024);
    const float* src; u16* dst; int CC, r0, c0;
    int R;
    if (bb < 1024) {       // W1: [C][512][1024], 128 tiles/comp (16 c x 8 r)
      int comp = bb >> 7, loc = bb & 127;
      R = LATD; CC = HID;
      c0 = (loc & 15) << 6; r0 = (loc >> 4) << 6;
      src = W1 + (size_t)comp*R*CC; dst = W1T + (size_t)comp*R*CC;
    } else {               // W2: [C][1024][512], 128 tiles/comp (8 c x 16 r)
      int b2 = bb - 1024;
      int comp = b2 >> 7, loc = b2 & 127;
      R = HID; CC = OUTD;
      c0 = (loc & 7) << 6; r0 = (loc >> 3) << 6;
      src = W2 + (size_t)comp*R*CC; dst = W2T + (size_t)comp*R*CC;
    }
    int tx = t & 63, ty = t >> 6;    // 16 row-groups of 64
    for (int rr = ty; rr < 64; rr += 16)
      tile[rr][tx] = src[(size_t)(r0+rr)*CC + c0 + tx];
    __syncthreads();
    for (int rr = ty; rr < 64; rr += 16)
      dst[(size_t)(c0+rr)*R + r0 + tx] = f2b(tile[tx][rr]);
  }
}

// ---------------- tile-mapped bf16 GEMM, 128x128, single-buffer (R3 structure) ----------------
// A: [*][K] bf16.  BT: [C][NB][K] bf16 (B^T).  4 waves, 4x4 16x16x32 MFMA frags,
// BK=64, global_load_lds w=16.  Grid 1-D, xcd=id&7 owns a contiguous slot chunk.
// STAGE1: A-rows GATHERED via order (Apack is in original sample order);
//         epilogue sigmoid -> bf16 H (bucket-ordered).
// STAGE2: A = H linear; epilogue +b2 -> fp32 scatter-store via order.
template<int K, int NB, int STAGE>
__global__ __launch_bounds__(256, 4)
void k_gemm(const u16* __restrict__ A, const u16* __restrict__ BT,
            const int* __restrict__ offsets, const int* __restrict__ ntiles,
            const int* __restrict__ map, const int* __restrict__ order,
            const float* __restrict__ bias,
            u16* __restrict__ Hout, float* __restrict__ Yout) {
  constexpr int NCB = NB/128;
  __shared__ u16 As[128*64];
  __shared__ u16 Bs[128*64];
  __shared__ int ord[128];

  const int id    = blockIdx.x;
  const int xcd   = id & 7;
  const int sub   = id >> 3;
  const int ncolb = sub % NCB;
  const int slot  = xcd*SLOT_CHUNK + sub / NCB;
  if (slot >= ntiles[0]) return;
  const int packed = map[slot];
  const int c      = packed >> 16;
  const int bstart = offsets[c];
  const int bend   = offsets[c+1];
  const int tile0  = bstart + (packed & 0xffff)*128;
  const int ncol0  = ncolb*128;

  const int tid  = threadIdx.x;
  const int wave = tid >> 6;
  const int lane = tid & 63;
  const int srow = (wave<<5) + (lane>>3);
  const int scol = (lane&7)<<3;

  if (STAGE == 2 && tid < 128) {
    int gr = tile0 + tid;
    ord[tid] = order[gr < bend ? gr : bstart];
  }

  size_t a_off[4], b_off[4];
  const size_t bbase = (size_t)c * NB * K;
  #pragma unroll
  for (int i = 0; i < 4; ++i) {
    int ar = tile0 + srow + (i<<3);
    if (ar >= bend) ar = bend - 1;           // clamp reads (stores guarded)
    int arow = (STAGE == 1) ? order[ar] : ar; // STAGE1: gather row via order
    a_off[i] = (size_t)arow * K + scol;
    b_off[i] = bbase + (size_t)(ncol0 + srow + (i<<3)) * K + scol;
  }

  const int wr   = (wave >> 1) << 6;
  const int wc   = (wave & 1) << 6;
  const int quad = lane >> 4;
  const int l16  = lane & 15;

  float bcol[4];
  #pragma unroll
  for (int ni = 0; ni < 4; ++ni)
    bcol[ni] = bias[(size_t)c*NB + ncol0 + wc + (ni<<4) + l16];

  f32x4 acc[4][4] = {};

  for (int k0 = 0; k0 < K; k0 += 64) {
    #pragma unroll
    for (int i = 0; i < 4; ++i)
      load_lds16(A + a_off[i] + k0, &As[((wave<<5) + (i<<3))<<6]);
    #pragma unroll
    for (int i = 0; i < 4; ++i)
      load_lds16(BT + b_off[i] + k0, &Bs[((wave<<5) + (i<<3))<<6]);
    __syncthreads();
    #pragma unroll
    for (int kk = 0; kk < 64; kk += 32) {
      bf16x8 af[4], bfr[4];
      #pragma unroll
      for (int mi = 0; mi < 4; ++mi)
        af[mi] = *reinterpret_cast<const bf16x8*>(&As[((wr + (mi<<4) + l16)<<6) + kk + (quad<<3)]);
      #pragma unroll
      for (int ni = 0; ni < 4; ++ni)
        bfr[ni] = *reinterpret_cast<const bf16x8*>(&Bs[((wc + (ni<<4) + l16)<<6) + kk + (quad<<3)]);
      #pragma unroll
      for (int mi = 0; mi < 4; ++mi)
        #pragma unroll
        for (int ni = 0; ni < 4; ++ni)
          acc[mi][ni] = __builtin_amdgcn_mfma_f32_16x16x32_bf16(af[mi], bfr[ni], acc[mi][ni], 0, 0, 0);
    }
    __syncthreads();
  }

  // epilogue: C/D layout col=lane&15, row=quad*4+reg
  #pragma unroll
  for (int mi = 0; mi < 4; ++mi) {
    #pragma unroll
    for (int r = 0; r < 4; ++r) {
      const int row_l = wr + (mi<<4) + (quad<<2) + r;
      const int grow  = tile0 + row_l;
      if (grow < bend) {
        #pragma unroll
        for (int ni = 0; ni < 4; ++ni) {
          const int col = ncol0 + wc + (ni<<4) + l16;
          float v = acc[mi][ni][r] + bcol[ni];
          if (STAGE == 1) {
            v = 1.0f / (1.0f + __expf(-v));
            Hout[(size_t)grow*NB + col] = f2b(v);
          } else {
            Yout[(size_t)ord[row_l]*NB + col] = v;
          }
        }
      }
    }
  }
}

// ---------------- fallback (ws too small): naive per-sample MLP ----------------
__global__ void k_naive(const float* __restrict__ eps, const int* __restrict__ idx,
                        const float* __restrict__ mu, const float* __restrict__ rho,
                        const float* __restrict__ W1, const float* __restrict__ b1,
                        const float* __restrict__ W2, const float* __restrict__ b2,
                        float* __restrict__ out) {
  __shared__ float lat[LATD];
  __shared__ float h[HID];
  int n = blockIdx.x, t = threadIdx.x;
  int c = idx[n];
  float r = rho[c];
  float sg = (r > 20.f) ? r : log1pf(expf(r));
  for (int d = t; d < LATD; d += 256) lat[d] = eps[(size_t)n*LATD+d]*sg + mu[(size_t)c*LATD+d];
  __syncthreads();
  for (int j = t; j < HID; j += 256) {
    float a = b1[(size_t)c*HID+j];
    const float* w = W1 + (size_t)c*LATD*HID + j;
    for (int d = 0; d < LATD; ++d) a += lat[d]*w[(size_t)d*HID];
    h[j] = 1.f/(1.f+expf(-a));
  }
  __syncthreads();
  for (int o = t; o < OUTD; o += 256) {
    float a = b2[(size_t)c*OUTD+o];
    const float* w = W2 + (size_t)c*HID*OUTD + o;
    for (int j = 0; j < HID; ++j) a += h[j]*w[(size_t)j*OUTD];
    out[(size_t)n*OUTD+o] = a;
  }
}

extern "C" void kernel_launch(void* const* d_in, const int* in_sizes, int n_in,
                              void* d_out, int out_size, void* d_ws, size_t ws_size,
                              hipStream_t stream) {
  const float* eps = (const float*)d_in[0];
  const int*   idx = (const int*)d_in[1];
  const float* mu  = (const float*)d_in[2];
  const float* rho = (const float*)d_in[3];
  const float* W1  = (const float*)d_in[4];
  const float* b1  = (const float*)d_in[5];
  const float* W2  = (const float*)d_in[6];
  const float* b2  = (const float*)d_in[7];
  float* out = (float*)d_out;

  if (ws_size < WS_NEEDED) {     // insurance only
    k_naive<<<NS, 256, 0, stream>>>(eps, idx, mu, rho, W1, b1, W2, b2, out);
    return;
  }

  char* ws = (char*)d_ws;
  int*   offsets = (int*)(ws + 0);
  int*   ntiles  = (int*)(ws + 96);
  int*   map     = (int*)(ws + 128);
  int*   order   = (int*)(ws + ORDER_OFF);
  u16*   Apack   = (u16*)(ws + APACK_OFF);
  u16*   W1T     = (u16*)(ws + W1T_OFF);
  u16*   W2T     = (u16*)(ws + W2T_OFF);
  u16*   Hws     = (u16*)(ws + H_OFF);

  // ONE prep dispatch: bucket (8 blocks) + pack (1024) + wtrans (2048)
  k_prep_all<<<NCOMP + 1024 + 2048, 1024, 0, stream>>>(
      idx, rho, eps, mu, W1, W2, offsets, ntiles, map, order, Apack, W1T, W2T);
  // GEMM1: gather-A [Nc x 512] @ [512 x 1024] -> sigmoid -> H (bf16, bucket order)
  k_gemm<LATD, HID, 1><<<8*SLOT_CHUNK*(HID/128), 256, 0, stream>>>(
      Apack, W1T, offsets, ntiles, map, order, b1, Hws, nullptr);
  // GEMM2: [Nc x 1024] @ [1024 x 512] -> +b2 -> fp32 scatter out
  k_gemm<HID, OUTD, 2><<<8*SLOT_CHUNK*(OUTD/128), 256, 0, stream>>>(
      Hws, W2T, offsets, ntiles, map, order, b2, nullptr, out);
}

// Round 7
// 182.129 us; speedup vs baseline: 1.6131x; 1.0604x over previous
//
#include <hip/hip_runtime.h>
#include <stdint.h>

#define NCOMP 8
#define LATD  512
#define HID   1024
#define OUTD  512
#define NS    16384

typedef unsigned short u16;
typedef __bf16 bf16x8 __attribute__((ext_vector_type(8)));
typedef float  f32x4  __attribute__((ext_vector_type(4)));

// ---- tile map: TM=128 for both gemms -> one shared map ----
#define MAPS       (NS/128 + NCOMP)        // 136 slots max
#define SLOT_CHUNK ((MAPS + 7)/8)          // 17 slots per XCD

// ---- workspace layout (bytes) ----
// offsets[9]@0, ntiles[1]@96, map[136]@128
#define ORDER_OFF  2048
#define APACK_OFF  (ORDER_OFF + NS*4)
#define W1T_OFF    (APACK_OFF + (size_t)NS*LATD*2)
#define W2T_OFF    (W1T_OFF + (size_t)NCOMP*LATD*HID*2)
#define H_OFF      (W2T_OFF + (size_t)NCOMP*HID*OUTD*2)
#define WS_NEEDED  (H_OFF + (size_t)NS*HID*2)

__device__ __forceinline__ u16 f2b(float f) {         // fp32 -> bf16 RNE
  unsigned int u = __builtin_bit_cast(unsigned int, f);
  u = (u + 0x7FFFu + ((u >> 16) & 1u)) >> 16;
  return (u16)u;
}

__device__ __forceinline__ void load_lds16(const void* g, void* l) {
  __builtin_amdgcn_global_load_lds((const __attribute__((address_space(1))) void*)g,
                                   (__attribute__((address_space(3))) void*)l, 16, 0, 0);
}

// ---------------- ONE prep dispatch ----------------
// blocks 0..7          : bucketing (block c owns comp c; no cross-block comm)
// blocks 8..1031       : pack A in ORIGINAL sample order (no `order` dependency)
// blocks 1032..3079    : W1/W2 transpose+convert fp32 -> bf16
__global__ __launch_bounds__(1024)
void k_prep_all(const int* __restrict__ idx, const float* __restrict__ rho,
                const float* __restrict__ eps, const float* __restrict__ mu,
                const float* __restrict__ W1, const float* __restrict__ W2,
                int* __restrict__ offsets, int* __restrict__ ntiles,
                int* __restrict__ map, int* __restrict__ order,
                u16* __restrict__ Apack, u16* __restrict__ W1T, u16* __restrict__ W2T) {
  __shared__ float tile[64][65];      // wtrans path
  __shared__ int hist_s[NCOMP];       // bucket path
  __shared__ int wtot[16];
  const int b = blockIdx.x;
  const int t = threadIdx.x;

  if (b < NCOMP) {
    // ---- bucketing: block c owns comp c ----
    const int c = b;
    const int wave = t >> 6, lane = t & 63;

    int my[16];
    #pragma unroll
    for (int i = 0; i < 16; ++i) my[i] = idx[t + (i << 10)];

    unsigned long long nib = 0;        // nibble-packed per-thread hist (<=16/comp)
    #pragma unroll
    for (int i = 0; i < 16; ++i) nib += 1ull << (my[i] << 2);

    if (t < NCOMP) hist_s[t] = 0;
    __syncthreads();

    #pragma unroll
    for (int cc = 0; cc < NCOMP; ++cc) {
      int v = (int)((nib >> (cc << 2)) & 15);
      #pragma unroll
      for (int d = 1; d < 64; d <<= 1) v += __shfl_xor(v, d);
      if (lane == 0) atomicAdd(&hist_s[cc], v);
    }

    int v = (int)((nib >> (c << 2)) & 15);
    int s = v;
    #pragma unroll
    for (int d = 1; d < 64; d <<= 1) {
      int u = __shfl_up(s, d);
      if (lane >= d) s += u;
    }
    if (lane == 63) wtot[wave] = s;
    __syncthreads();

    int wbase = 0;
    for (int w = 0; w < wave; ++w) wbase += wtot[w];
    int off_c = 0;
    #pragma unroll
    for (int cc = 0; cc < NCOMP; ++cc) if (cc < c) off_c += hist_s[cc];

    int pos = off_c + wbase + (s - v);
    #pragma unroll
    for (int i = 0; i < 16; ++i)
      if (my[i] == c) order[pos++] = t + (i << 10);

    if (t == 0) {
      if (c == 0) {
        int a = 0;
        for (int cc = 0; cc < NCOMP; ++cc) { offsets[cc] = a; a += hist_s[cc]; }
        offsets[NCOMP] = a;
        int tot = 0;
        for (int cc = 0; cc < NCOMP; ++cc) tot += (hist_s[cc] + 127) >> 7;
        ntiles[0] = tot;
      }
      int mb = 0;
      for (int cc = 0; cc < c; ++cc) mb += (hist_s[cc] + 127) >> 7;
      int nt = (hist_s[c] + 127) >> 7;
      for (int m = 0; m < nt; ++m) map[mb + m] = (c << 16) | m;
    }
  } else if (b < NCOMP + 1024) {
    // ---- pack: lat[i] = eps[i]*softplus(rho[idx[i]]) + mu[idx[i]], original order ----
    int g = (b - NCOMP) * 1024 + t;
    int i = g >> 6;                   // sample (64 threads/sample)
    int d = (g & 63) << 3;
    int c = idx[i];                   // broadcast within the 64-thread group
    float r = rho[c];
    float sg = (r > 20.f) ? r : log1pf(expf(r));
    const float4* ep = reinterpret_cast<const float4*>(eps + (size_t)i*LATD + d);
    const float4* mp = reinterpret_cast<const float4*>(mu  + (size_t)c*LATD + d);
    float4 e0 = ep[0], e1 = ep[1], m0 = mp[0], m1 = mp[1];
    unsigned o0 = f2b(e0.x*sg+m0.x), o1 = f2b(e0.y*sg+m0.y), o2 = f2b(e0.z*sg+m0.z), o3 = f2b(e0.w*sg+m0.w);
    unsigned o4 = f2b(e1.x*sg+m1.x), o5 = f2b(e1.y*sg+m1.y), o6 = f2b(e1.z*sg+m1.z), o7 = f2b(e1.w*sg+m1.w);
    uint4 pk;
    pk.x = o0 | (o1<<16); pk.y = o2 | (o3<<16); pk.z = o4 | (o5<<16); pk.w = o6 | (o7<<16);
    *reinterpret_cast<uint4*>(Apack + (size_t)i*LATD + d) = pk;
  } else {
    // ---- transpose+convert: W [C][R][CC] fp32 -> WT [C][CC][R] bf16 ----
    int bb = b - (NCOMP + 1024);
    const float* src; u16* dst; int CC, r0, c0;
    int R;
    if (bb < 1024) {       // W1: [C][512][1024], 128 tiles/comp (16 c x 8 r)
      int comp = bb >> 7, loc = bb & 127;
      R = LATD; CC = HID;
      c0 = (loc & 15) << 6; r0 = (loc >> 4) << 6;
      src = W1 + (size_t)comp*R*CC; dst = W1T + (size_t)comp*R*CC;
    } else {               // W2: [C][1024][512], 128 tiles/comp (8 c x 16 r)
      int b2 = bb - 1024;
      int comp = b2 >> 7, loc = b2 & 127;
      R = HID; CC = OUTD;
      c0 = (loc & 7) << 6; r0 = (loc >> 3) << 6;
      src = W2 + (size_t)comp*R*CC; dst = W2T + (size_t)comp*R*CC;
    }
    int tx = t & 63, ty = t >> 6;    // 16 row-groups of 64
    for (int rr = ty; rr < 64; rr += 16)
      tile[rr][tx] = src[(size_t)(r0+rr)*CC + c0 + tx];
    __syncthreads();
    for (int rr = ty; rr < 64; rr += 16)
      dst[(size_t)(c0+rr)*R + r0 + tx] = f2b(tile[tx][rr]);
  }
}

// ---------------- tile-mapped bf16 GEMM, 128x128, swizzled LDS ----------------
// A: [*][K] bf16.  BT: [C][NB][K] bf16 (B^T).  4 waves, 4x4 16x16x32 MFMA frags,
// BK=64, global_load_lds w=16.
// LDS layout XOR-swizzle (bank-conflict fix): LDS[r][c] = G[r][c ^ (r&7)]
// (16B chunks). Implemented by swizzling the DMA *source* chunk per lane
// (dest is lane-linear by HW). Fragment reads use slot kc ^ (l16&7): 2 lanes
// per bank group (free) instead of 16 (2x LDS-pipe penalty, 6.5M conflict cyc).
// Grid 1-D, xcd=id&7 owns a contiguous slot chunk.
// STAGE1: A-rows gathered via order; epilogue sigmoid -> bf16 H (bucket order).
// STAGE2: A = H linear; epilogue +b2 -> fp32 scatter-store via order.
template<int K, int NB, int STAGE>
__global__ __launch_bounds__(256, 4)
void k_gemm(const u16* __restrict__ A, const u16* __restrict__ BT,
            const int* __restrict__ offsets, const int* __restrict__ ntiles,
            const int* __restrict__ map, const int* __restrict__ order,
            const float* __restrict__ bias,
            u16* __restrict__ Hout, float* __restrict__ Yout) {
  constexpr int NCB = NB/128;
  __shared__ u16 As[128*64];
  __shared__ u16 Bs[128*64];
  __shared__ int ord[128];

  const int id    = blockIdx.x;
  const int xcd   = id & 7;
  const int sub   = id >> 3;
  const int ncolb = sub % NCB;
  const int slot  = xcd*SLOT_CHUNK + sub / NCB;
  if (slot >= ntiles[0]) return;
  const int packed = map[slot];
  const int c      = packed >> 16;
  const int bstart = offsets[c];
  const int bend   = offsets[c+1];
  const int tile0  = bstart + (packed & 0xffff)*128;
  const int ncol0  = ncolb*128;

  const int tid  = threadIdx.x;
  const int wave = tid >> 6;
  const int lane = tid & 63;
  const int srow = (wave<<5) + (lane>>3);               // staging row (local)
  const int scol = ((lane & 7) ^ ((lane >> 3) & 7)) << 3; // swizzled source chunk

  if (STAGE == 2 && tid < 128) {
    int gr = tile0 + tid;
    ord[tid] = order[gr < bend ? gr : bstart];
  }

  size_t a_off[4], b_off[4];
  const size_t bbase = (size_t)c * NB * K;
  #pragma unroll
  for (int i = 0; i < 4; ++i) {
    int ar = tile0 + srow + (i<<3);
    if (ar >= bend) ar = bend - 1;           // clamp reads (stores guarded)
    int arow = (STAGE == 1) ? order[ar] : ar; // STAGE1: gather row via order
    a_off[i] = (size_t)arow * K + scol;
    b_off[i] = bbase + (size_t)(ncol0 + srow + (i<<3)) * K + scol;
  }

  const int wr   = (wave >> 1) << 6;
  const int wc   = (wave & 1) << 6;
  const int quad = lane >> 4;
  const int l16  = lane & 15;
  const int sw   = l16 & 7;                  // read-side swizzle key (= row&7)

  float bcol[4];
  #pragma unroll
  for (int ni = 0; ni < 4; ++ni)
    bcol[ni] = bias[(size_t)c*NB + ncol0 + wc + (ni<<4) + l16];

  f32x4 acc[4][4] = {};

  for (int k0 = 0; k0 < K; k0 += 64) {
    #pragma unroll
    for (int i = 0; i < 4; ++i)
      load_lds16(A + a_off[i] + k0, &As[((wave<<5) + (i<<3))<<6]);
    #pragma unroll
    for (int i = 0; i < 4; ++i)
      load_lds16(BT + b_off[i] + k0, &Bs[((wave<<5) + (i<<3))<<6]);
    __syncthreads();
    #pragma unroll
    for (int kk = 0; kk < 64; kk += 32) {
      const int kc = (kk >> 3) + quad;       // desired 16B chunk index
      const int sc = (kc ^ sw) << 3;         // swizzled LDS slot (elems)
      bf16x8 af[4], bfr[4];
      #pragma unroll
      for (int mi = 0; mi < 4; ++mi)
        af[mi] = *reinterpret_cast<const bf16x8*>(&As[((wr + (mi<<4) + l16)<<6) + sc]);
      #pragma unroll
      for (int ni = 0; ni < 4; ++ni)
        bfr[ni] = *reinterpret_cast<const bf16x8*>(&Bs[((wc + (ni<<4) + l16)<<6) + sc]);
      #pragma unroll
      for (int mi = 0; mi < 4; ++mi)
        #pragma unroll
        for (int ni = 0; ni < 4; ++ni)
          acc[mi][ni] = __builtin_amdgcn_mfma_f32_16x16x32_bf16(af[mi], bfr[ni], acc[mi][ni], 0, 0, 0);
    }
    __syncthreads();
  }

  // epilogue: C/D layout col=lane&15, row=quad*4+reg
  #pragma unroll
  for (int mi = 0; mi < 4; ++mi) {
    #pragma unroll
    for (int r = 0; r < 4; ++r) {
      const int row_l = wr + (mi<<4) + (quad<<2) + r;
      const int grow  = tile0 + row_l;
      if (grow < bend) {
        #pragma unroll
        for (int ni = 0; ni < 4; ++ni) {
          const int col = ncol0 + wc + (ni<<4) + l16;
          float v = acc[mi][ni][r] + bcol[ni];
          if (STAGE == 1) {
            v = 1.0f / (1.0f + __expf(-v));
            Hout[(size_t)grow*NB + col] = f2b(v);
          } else {
            Yout[(size_t)ord[row_l]*NB + col] = v;
          }
        }
      }
    }
  }
}

// ---------------- fallback (ws too small): naive per-sample MLP ----------------
__global__ void k_naive(const float* __restrict__ eps, const int* __restrict__ idx,
                        const float* __restrict__ mu, const float* __restrict__ rho,
                        const float* __restrict__ W1, const float* __restrict__ b1,
                        const float* __restrict__ W2, const float* __restrict__ b2,
                        float* __restrict__ out) {
  __shared__ float lat[LATD];
  __shared__ float h[HID];
  int n = blockIdx.x, t = threadIdx.x;
  int c = idx[n];
  float r = rho[c];
  float sg = (r > 20.f) ? r : log1pf(expf(r));
  for (int d = t; d < LATD; d += 256) lat[d] = eps[(size_t)n*LATD+d]*sg + mu[(size_t)c*LATD+d];
  __syncthreads();
  for (int j = t; j < HID; j += 256) {
    float a = b1[(size_t)c*HID+j];
    const float* w = W1 + (size_t)c*LATD*HID + j;
    for (int d = 0; d < LATD; ++d) a += lat[d]*w[(size_t)d*HID];
    h[j] = 1.f/(1.f+expf(-a));
  }
  __syncthreads();
  for (int o = t; o < OUTD; o += 256) {
    float a = b2[(size_t)c*OUTD+o];
    const float* w = W2 + (size_t)c*HID*OUTD + o;
    for (int j = 0; j < HID; ++j) a += h[j]*w[(size_t)j*OUTD];
    out[(size_t)n*OUTD+o] = a;
  }
}

extern "C" void kernel_launch(void* const* d_in, const int* in_sizes, int n_in,
                              void* d_out, int out_size, void* d_ws, size_t ws_size,
                              hipStream_t stream) {
  const float* eps = (const float*)d_in[0];
  const int*   idx = (const int*)d_in[1];
  const float* mu  = (const float*)d_in[2];
  const float* rho = (const float*)d_in[3];
  const float* W1  = (const float*)d_in[4];
  const float* b1  = (const float*)d_in[5];
  const float* W2  = (const float*)d_in[6];
  const float* b2  = (const float*)d_in[7];
  float* out = (float*)d_out;

  if (ws_size < WS_NEEDED) {     // insurance only
    k_naive<<<NS, 256, 0, stream>>>(eps, idx, mu, rho, W1, b1, W2, b2, out);
    return;
  }

  char* ws = (char*)d_ws;
  int*   offsets = (int*)(ws + 0);
  int*   ntiles  = (int*)(ws + 96);
  int*   map     = (int*)(ws + 128);
  int*   order   = (int*)(ws + ORDER_OFF);
  u16*   Apack   = (u16*)(ws + APACK_OFF);
  u16*   W1T     = (u16*)(ws + W1T_OFF);
  u16*   W2T     = (u16*)(ws + W2T_OFF);
  u16*   Hws     = (u16*)(ws + H_OFF);

  // ONE prep dispatch: bucket (8 blocks) + pack (1024) + wtrans (2048)
  k_prep_all<<<NCOMP + 1024 + 2048, 1024, 0, stream>>>(
      idx, rho, eps, mu, W1, W2, offsets, ntiles, map, order, Apack, W1T, W2T);
  // GEMM1: gather-A [Nc x 512] @ [512 x 1024] -> sigmoid -> H (bf16, bucket order)
  k_gemm<LATD, HID, 1><<<8*SLOT_CHUNK*(HID/128), 256, 0, stream>>>(
      Apack, W1T, offsets, ntiles, map, order, b1, Hws, nullptr);
  // GEMM2: [Nc x 1024] @ [1024 x 512] -> +b2 -> fp32 scatter out
  k_gemm<HID, OUTD, 2><<<8*SLOT_CHUNK*(OUTD/128), 256, 0, stream>>>(
      Hws, W2T, offsets, ntiles, map, order, b2, nullptr, out);
}